// Round 9
// baseline (181.756 us; speedup 1.0000x reference)
//
#include <hip/hip_runtime.h>
#include <math.h>

#define D 128
#define STATS_BLOCKS 512
#define SCAN_CHUNK 256

typedef __attribute__((ext_vector_type(8))) short short8;
typedef __attribute__((ext_vector_type(4))) float f32x4;

__device__ __forceinline__ unsigned short f2bf(float f) {
    unsigned u = __float_as_uint(f);
    unsigned r = (u + 0x7fff + ((u >> 16) & 1)) >> 16;   // RNE
    return (unsigned short)r;
}
__device__ __forceinline__ float bflo(unsigned u) { return __uint_as_float(u << 16); }
__device__ __forceinline__ float bfhi(unsigned u) { return __uint_as_float(u & 0xffff0000u); }

// ---------------- pack Wl|Wr into fragment-major bf16 ----------------
__global__ __launch_bounds__(256) void pack_w_k(const float* __restrict__ Wl,
    const float* __restrict__ Wr, unsigned short* __restrict__ wpack)
{
    const int lane = threadIdx.x & 63;
    const int wv = threadIdx.x >> 6;
    const int slot = blockIdx.x * 4 + wv;     // grid 16 -> slots 0..63
    const int ct = slot >> 2;
    const int kt = slot & 3;
    const float* W = (ct < 8) ? Wl : Wr;
    const int cb = (ct & 7) * 16 + (lane & 15);
    const int kb = kt * 32 + (lane >> 4) * 8;
    unsigned short v[8];
#pragma unroll
    for (int i = 0; i < 8; i++) v[i] = f2bf(W[(size_t)(kb + i) * D + cb]);
    *(uint4*)(wpack + ((size_t)slot << 9) + lane * 8) = *(uint4*)v;
}

// ---------------- MFMA GEMM: xl(bf16 packed) = x@Wl+bl, xr(f32) = x@Wr+br ----------------
__global__ __launch_bounds__(256) void gemm_mfma_k(const float* __restrict__ x,
    const unsigned short* __restrict__ wpack, const float* __restrict__ bl,
    const float* __restrict__ br, unsigned* __restrict__ xlb,
    float* __restrict__ xr, int n)
{
    const int lane = threadIdx.x & 63;
    const int wv = threadIdx.x >> 6;
    const int rt = blockIdx.x * 4 + wv;          // 16-row tile index
    if (rt * 16 >= n) return;
    const int r0 = rt * 16;
    const int ra = r0 + (lane & 15);
    const int r = ra < n ? ra : n - 1;
    const int ko = (lane >> 4) * 8;

    short8 a[4];
#pragma unroll
    for (int kt = 0; kt < 4; kt++) {
        const float* px = x + (size_t)r * D + kt * 32 + ko;
        float4 lo = *(const float4*)px;
        float4 hi = *(const float4*)(px + 4);
        short8 t;
        t[0] = (short)f2bf(lo.x); t[1] = (short)f2bf(lo.y);
        t[2] = (short)f2bf(lo.z); t[3] = (short)f2bf(lo.w);
        t[4] = (short)f2bf(hi.x); t[5] = (short)f2bf(hi.y);
        t[6] = (short)f2bf(hi.z); t[7] = (short)f2bf(hi.w);
        a[kt] = t;
    }

    f32x4 acc[16];
#pragma unroll
    for (int i = 0; i < 16; i++) acc[i] = (f32x4){0.f, 0.f, 0.f, 0.f};

#pragma unroll
    for (int kt = 0; kt < 4; kt++) {
#pragma unroll
        for (int ct = 0; ct < 16; ct++) {
            short8 b = *(const short8*)(wpack + (((size_t)(ct * 4 + kt)) << 9) + lane * 8);
            acc[ct] = __builtin_amdgcn_mfma_f32_16x16x32_bf16(a[kt], b, acc[ct], 0, 0, 0);
        }
    }

    const int colb = lane & 15;
    const int rbase = r0 + (lane >> 4) * 4;
#pragma unroll
    for (int ct = 8; ct < 16; ct++) {
        const int c = (ct - 8) * 16 + colb;
        const float bb = br[c];
#pragma unroll
        for (int reg = 0; reg < 4; reg++) {
            const int row = rbase + reg;
            if (row < n) xr[(size_t)row * D + c] = acc[ct][reg] + bb;
        }
    }
#pragma unroll
    for (int ct = 0; ct < 8; ct++) {
        const int c = ct * 16 + colb;
        const float bb = bl[c];
#pragma unroll
        for (int reg = 0; reg < 4; reg++) {
            unsigned mybf = f2bf(acc[ct][reg] + bb);
            unsigned other = (unsigned)__shfl_xor((int)mybf, 1);
            if ((lane & 1) == 0) {
                const int row = rbase + reg;
                if (row < n) xlb[(size_t)row * 64 + (c >> 1)] = mybf | (other << 16);
            }
        }
    }
}

// ---------------- CSR build: histogram ----------------
__global__ __launch_bounds__(256) void hist_k(const int* __restrict__ ei,
    int* __restrict__ deg, int E)
{
    int e = blockIdx.x * blockDim.x + threadIdx.x;
    if (e < E) atomicAdd(&deg[ei[E + e]], 1);
}

// ---------------- scan stage 1: per-block chunk sums + degree histogram ----------------
__global__ __launch_bounds__(256) void scan_sum_k(const int* __restrict__ deg,
    int* __restrict__ bsum, int* __restrict__ deghist, int n)
{
    __shared__ int lh[256];
    const int t = threadIdx.x;
    lh[t] = 0;
    __syncthreads();
    const int i = blockIdx.x * SCAN_CHUNK + t;
    int s = 0;
    if (i < n) {
        s = deg[i];
        atomicAdd(&lh[min(s, 255)], 1);
    }
#pragma unroll
    for (int off = 32; off > 0; off >>= 1) s += __shfl_xor(s, off);
    __shared__ int ws_[4];
    const int lane = t & 63, w = t >> 6;
    if (lane == 0) ws_[w] = s;
    __syncthreads();
    if (t == 0) bsum[blockIdx.x] = ws_[0] + ws_[1] + ws_[2] + ws_[3];
    if (lh[t]) atomicAdd(&deghist[t], lh[t]);
}

// ---------------- scan stage 2: exclusive scan of block sums + degree-bin offsets ----------------
__global__ __launch_bounds__(256) void scan_off_k(const int* __restrict__ bsum,
    int* __restrict__ boff, int* __restrict__ rowptr,
    const int* __restrict__ deghist, int* __restrict__ degcur, int nb, int n)
{
    const int t = threadIdx.x;
    const int lane = t & 63, w = t >> 6;
    // --- scan of block sums ---
    int v = (t < nb) ? bsum[t] : 0;
    int inc = v;
#pragma unroll
    for (int off = 1; off < 64; off <<= 1) {
        int u = __shfl_up(inc, off);
        if (lane >= off) inc += u;
    }
    __shared__ int wsum[4], wpre[4];
    if (lane == 63) wsum[w] = inc;
    __syncthreads();
    if (t == 0) {
        int r = 0;
#pragma unroll
        for (int j = 0; j < 4; j++) { wpre[j] = r; r += wsum[j]; }
        rowptr[n] = r;
    }
    __syncthreads();
    if (t < nb) boff[t] = inc - v + wpre[w];
    // --- exclusive scan of degree histogram ---
    int dv = deghist[t];
    int dinc = dv;
#pragma unroll
    for (int off = 1; off < 64; off <<= 1) {
        int u = __shfl_up(dinc, off);
        if (lane >= off) dinc += u;
    }
    __shared__ int w2sum[4], w2pre[4];
    if (lane == 63) w2sum[w] = dinc;
    __syncthreads();
    if (t == 0) {
        int r = 0;
#pragma unroll
        for (int j = 0; j < 4; j++) { w2pre[j] = r; r += w2sum[j]; }
    }
    __syncthreads();
    degcur[t] = dinc - dv + w2pre[w];
}

// ---------------- scan stage 3: in-block scan + offset + degree-sorted node order ----------------
__global__ __launch_bounds__(256) void scan_fin_k(int* __restrict__ deg,
    const int* __restrict__ boff, int* __restrict__ rowptr,
    int* __restrict__ degcur, int* __restrict__ nodeord, int n)
{
    __shared__ int wsum[4], wpre[4];
    __shared__ int lh[256], lbase[256];
    const int t = threadIdx.x;
    const int i = blockIdx.x * SCAN_CHUNK + t;
    lh[t] = 0;
    int v = (i < n) ? deg[i] : 0;
    const int bin = min(v, 255);
    const int lane = t & 63, w = t >> 6;
    int inc = v;
#pragma unroll
    for (int off = 1; off < 64; off <<= 1) {
        int u = __shfl_up(inc, off);
        if (lane >= off) inc += u;
    }
    if (lane == 63) wsum[w] = inc;
    __syncthreads();
    if (t == 0) {
        int r = 0;
#pragma unroll
        for (int j = 0; j < 4; j++) { wpre[j] = r; r += wsum[j]; }
    }
    __syncthreads();
    int rank = 0;
    if (i < n) {
        rank = atomicAdd(&lh[bin], 1);
        int ex = inc - v + wpre[w] + boff[blockIdx.x];
        rowptr[i] = ex;
        deg[i] = ex;                 // scatter cursor
    }
    __syncthreads();
    lbase[t] = lh[t] ? atomicAdd(&degcur[t], lh[t]) : 0;
    __syncthreads();
    if (i < n) nodeord[lbase[bin] + rank] = i;
}

// ---------------- CSR build: scatter {src, ea} pairs into dst-grouped order ----------------
__global__ __launch_bounds__(256) void scatter_k(const int* __restrict__ ei,
    const float* __restrict__ ea, int* __restrict__ cursor,
    uint2* __restrict__ edges, int E)
{
    int e = blockIdx.x * blockDim.x + threadIdx.x;
    if (e >= E) return;
    int dst = ei[E + e];
    int pos = atomicAdd(&cursor[dst], 1);
    edges[pos] = make_uint2((unsigned)ei[e], __float_as_uint(ea[e]));
}

// ---------------- fused edge logits + online softmax + aggregate ----------------
// one 16-lane group per dst node (4 independent nodes/wave, no cross-group
// merge); nodes processed in degree-sorted order so the wave's 4 nodes have
// near-equal degree (minimal raggedness). Lane owns 8 features. Output is
// packed bf16 into aggout (d_out's first half).
__global__ __launch_bounds__(256) void agg_k(const unsigned* __restrict__ xlb,
    const float* __restrict__ xr, const int* __restrict__ rowptr,
    const uint2* __restrict__ edges, const float* __restrict__ We,
    const float* __restrict__ att, const int* __restrict__ nodeord,
    unsigned* __restrict__ aggout, int n)
{
    const int gg = (blockIdx.x * 256 + threadIdx.x) >> 4;
    const int li = threadIdx.x & 15;
    if (gg >= n) return;
    const int v = nodeord[gg];
    const int beg = rowptr[v];
    const int end = rowptr[v + 1];
    const int f0 = li * 8;

    float xrv[8], wev[8], atv[8];
    {
        float4 a0 = *(const float4*)(xr + (size_t)v * D + f0);
        float4 a1 = *(const float4*)(xr + (size_t)v * D + f0 + 4);
        xrv[0]=a0.x; xrv[1]=a0.y; xrv[2]=a0.z; xrv[3]=a0.w;
        xrv[4]=a1.x; xrv[5]=a1.y; xrv[6]=a1.z; xrv[7]=a1.w;
        float4 w0 = *(const float4*)(We + f0);
        float4 w1 = *(const float4*)(We + f0 + 4);
        wev[0]=w0.x; wev[1]=w0.y; wev[2]=w0.z; wev[3]=w0.w;
        wev[4]=w1.x; wev[5]=w1.y; wev[6]=w1.z; wev[7]=w1.w;
        float4 t0 = *(const float4*)(att + f0);
        float4 t1 = *(const float4*)(att + f0 + 4);
        atv[0]=t0.x; atv[1]=t0.y; atv[2]=t0.z; atv[3]=t0.w;
        atv[4]=t1.x; atv[5]=t1.y; atv[6]=t1.z; atv[7]=t1.w;
    }

    float m = -1e30f, s = 0.f;
    float acc[8];
#pragma unroll
    for (int k = 0; k < 8; k++) acc[k] = 0.f;

    int j = beg;
    uint2 e2 = make_uint2(0u, 0u);
    uint4 xb4 = make_uint4(0u, 0u, 0u, 0u);
    if (j < end) {
        e2 = edges[j];
        xb4 = *(const uint4*)(xlb + (size_t)e2.x * 64 + li * 4);
    }
    while (j < end) {
        const int jn = j + 1;
        const int jc = jn < end ? jn : end - 1;     // clamped prefetch
        const uint2 e2n = edges[jc];
        const uint4 xbn = *(const uint4*)(xlb + (size_t)e2n.x * 64 + li * 4);

        const float eav = __uint_as_float(e2.y);
        float xv[8];
        xv[0] = bflo(xb4.x); xv[1] = bfhi(xb4.x);
        xv[2] = bflo(xb4.y); xv[3] = bfhi(xb4.y);
        xv[4] = bflo(xb4.z); xv[5] = bfhi(xb4.z);
        xv[6] = bflo(xb4.w); xv[7] = bfhi(xb4.w);

        float p = 0.f;
#pragma unroll
        for (int k = 0; k < 8; k++) {
            float t = fmaf(eav, wev[k], xrv[k]) + xv[k];
            t = fmaxf(t, 0.2f * t);                 // leaky relu
            p = fmaf(t, atv[k], p);
        }
#pragma unroll
        for (int off = 8; off >= 1; off >>= 1) p += __shfl_xor(p, off);

        const float pm = fmaxf(m, p);
        const float sc = __expf(m - pm);
        const float w  = __expf(p - pm);
        s = s * sc + w;
#pragma unroll
        for (int k = 0; k < 8; k++) acc[k] = fmaf(acc[k], sc, w * xv[k]);
        m = pm;

        e2 = e2n; xb4 = xbn; j = jn;
    }

    const float inv = 1.f / (s + 1e-16f);           // deg==0 -> acc=0 -> out=0
    unsigned o0 = (unsigned)f2bf(acc[0]*inv) | ((unsigned)f2bf(acc[1]*inv) << 16);
    unsigned o1 = (unsigned)f2bf(acc[2]*inv) | ((unsigned)f2bf(acc[3]*inv) << 16);
    unsigned o2 = (unsigned)f2bf(acc[4]*inv) | ((unsigned)f2bf(acc[5]*inv) << 16);
    unsigned o3 = (unsigned)f2bf(acc[6]*inv) | ((unsigned)f2bf(acc[7]*inv) << 16);
    *(uint4*)(aggout + (size_t)v * 64 + li * 4) = make_uint4(o0, o1, o2, o3);
}

// ---------------- residual + GELU(erf) + BN stats (bf16 in/out, atomic-free) ----------------
__global__ __launch_bounds__(256) void gelu_stats_k(const float* __restrict__ x,
    const float* __restrict__ bias, const unsigned* __restrict__ aggout,
    unsigned* __restrict__ hbf, float* __restrict__ partials, int total4)
{
    const int t = threadIdx.x;
    const int c0 = (t & 31) * 4;
    const float4 bv = *(const float4*)&bias[c0];
    float sum[4] = {0.f, 0.f, 0.f, 0.f}, sq[4] = {0.f, 0.f, 0.f, 0.f};
    const int stride = gridDim.x * blockDim.x;
    for (int i4 = blockIdx.x * blockDim.x + t; i4 < total4; i4 += stride) {
        float4 xv = ((const float4*)x)[i4];
        uint2 ag = *(const uint2*)(aggout + (size_t)i4 * 2);
        float hv[4] = {xv.x + bflo(ag.x) + bv.x, xv.y + bfhi(ag.x) + bv.y,
                       xv.z + bflo(ag.y) + bv.z, xv.w + bfhi(ag.y) + bv.w};
        float res[4];
#pragma unroll
        for (int j = 0; j < 4; j++) {
            float ge = 0.5f * hv[j] * (1.f + erff(hv[j] * 0.70710678118654752f));
            res[j] = ge;
            sum[j] += ge;
            sq[j] += ge * ge;
        }
        uint2 hp;
        hp.x = (unsigned)f2bf(res[0]) | ((unsigned)f2bf(res[1]) << 16);
        hp.y = (unsigned)f2bf(res[2]) | ((unsigned)f2bf(res[3]) << 16);
        *(uint2*)(hbf + (size_t)i4 * 2) = hp;
    }
    __shared__ float red[8][128];
    const int slot = t >> 5;
#pragma unroll
    for (int j = 0; j < 4; j++) red[slot][c0 + j] = sum[j];
    __syncthreads();
    if (t < 128) {
        float tot = 0.f;
#pragma unroll
        for (int s2 = 0; s2 < 8; s2++) tot += red[s2][t];
        partials[(size_t)t * STATS_BLOCKS + blockIdx.x] = tot;
    }
    __syncthreads();
#pragma unroll
    for (int j = 0; j < 4; j++) red[slot][c0 + j] = sq[j];
    __syncthreads();
    if (t < 128) {
        float tot = 0.f;
#pragma unroll
        for (int s2 = 0; s2 < 8; s2++) tot += red[s2][t];
        partials[(size_t)(128 + t) * STATS_BLOCKS + blockIdx.x] = tot;
    }
}

// ---------------- reduce partials + fold BN params ----------------
__global__ __launch_bounds__(256) void bn_reduce_params_k(const float* __restrict__ partials,
    const float* __restrict__ gamma, const float* __restrict__ beta,
    float* __restrict__ ab, float n)
{
    const int c = blockIdx.x;      // 0..127
    const int t = threadIdx.x;     // 256
    float s = 0.f, q = 0.f;
    for (int b = t; b < STATS_BLOCKS; b += 256) {
        s += partials[(size_t)c * STATS_BLOCKS + b];
        q += partials[(size_t)(128 + c) * STATS_BLOCKS + b];
    }
#pragma unroll
    for (int off = 32; off > 0; off >>= 1) {
        s += __shfl_xor(s, off);
        q += __shfl_xor(q, off);
    }
    __shared__ float ss[4], qq[4];
    const int lane = t & 63, w = t >> 6;
    if (lane == 0) { ss[w] = s; qq[w] = q; }
    __syncthreads();
    if (t == 0) {
        float S = ss[0] + ss[1] + ss[2] + ss[3];
        float Q = qq[0] + qq[1] + qq[2] + qq[3];
        float mean = S / n;
        float var = Q / n - mean * mean;
        float a = rsqrtf(var + 1e-5f) * gamma[c];
        ab[c] = a;
        ab[c + 128] = beta[c] - mean * a;
    }
}

// ---------------- BN apply (bf16 h -> f32 out) ----------------
__global__ __launch_bounds__(256) void bn_apply_k(const unsigned* __restrict__ hbf,
    float* __restrict__ out, const float* __restrict__ ab, int total4)
{
    int i4 = blockIdx.x * blockDim.x + threadIdx.x;
    if (i4 >= total4) return;
    int cg = i4 & 31;
    uint2 hp = *(const uint2*)(hbf + (size_t)i4 * 2);
    float4 a = ((const float4*)ab)[cg];
    float4 b = ((const float4*)(ab + 128))[cg];
    ((float4*)out)[i4] = make_float4(bflo(hp.x) * a.x + b.x, bfhi(hp.x) * a.y + b.y,
                                     bflo(hp.y) * a.z + b.z, bfhi(hp.y) * a.w + b.w);
}

extern "C" void kernel_launch(void* const* d_in, const int* in_sizes, int n_in,
                              void* d_out, int out_size, void* d_ws, size_t ws_size,
                              hipStream_t stream)
{
    const float* x    = (const float*)d_in[0];
    const int*   ei   = (const int*)d_in[1];
    const float* ea   = (const float*)d_in[2];
    const float* Wl   = (const float*)d_in[3];
    const float* bl   = (const float*)d_in[4];
    const float* Wr   = (const float*)d_in[5];
    const float* br   = (const float*)d_in[6];
    const float* We   = (const float*)d_in[7];
    const float* att  = (const float*)d_in[8];
    const float* bias = (const float*)d_in[9];
    const float* gamma= (const float*)d_in[10];
    const float* beta = (const float*)d_in[11];
    float* out = (float*)d_out;

    const int n = in_sizes[0] / D;
    const int E = in_sizes[1] / 2;
    const int nb = (n + SCAN_CHUNK - 1) / SCAN_CHUNK;

    char* ws = (char*)d_ws;
    unsigned short* wpack = (unsigned short*)ws;        // 32768 bf16 (64 KB)
    unsigned* xlb = (unsigned*)(ws + 65536);            // n*64 uints (bf16 xl); reused as hbf
    float* xr = (float*)(xlb + (size_t)n * 64);         // n*D floats
    int* deg = (int*)(xr + (size_t)n * D);              // n (becomes cursor)
    int* rowptr = deg + n;                              // n+1
    int* deghist = rowptr + n + 1;                      // 256
    int* degcur = deghist + 256;                        // 256
    int* nodeord = degcur + 256;                        // n
    int* bsum = nodeord + n;                            // nb
    int* boff = bsum + nb;                              // nb
    uintptr_t ep = ((uintptr_t)(boff + nb) + 7) & ~(uintptr_t)7;
    uint2* edges = (uint2*)ep;                          // E uint2
    float* partials = (float*)(edges + E);              // 256*STATS_BLOCKS
    float* ab = partials + 256 * STATS_BLOCKS;          // 256

    unsigned* aggout = (unsigned*)d_out;                // n*64 uints (bf16), first half of out
    unsigned* hbf = xlb;                                // reuse after agg_k

    // zero deg + rowptr + deghist (contiguous)
    hipMemsetAsync(deg, 0, (size_t)(2 * n + 1 + 256) * 4, stream);

    pack_w_k<<<16, 256, 0, stream>>>(Wl, Wr, wpack);
    const int nrt = (n + 15) / 16;
    gemm_mfma_k<<<(nrt + 3) / 4, 256, 0, stream>>>(x, wpack, bl, br, xlb, xr, n);
    hist_k<<<(E + 255) / 256, 256, 0, stream>>>(ei, deg, E);
    scan_sum_k<<<nb, 256, 0, stream>>>(deg, bsum, deghist, n);
    scan_off_k<<<1, 256, 0, stream>>>(bsum, boff, rowptr, deghist, degcur, nb, n);
    scan_fin_k<<<nb, 256, 0, stream>>>(deg, boff, rowptr, degcur, nodeord, n);
    scatter_k<<<(E + 255) / 256, 256, 0, stream>>>(ei, ea, deg, edges, E);
    agg_k<<<(n + 15) / 16, 256, 0, stream>>>(xlb, xr, rowptr, edges, We, att, nodeord, aggout, n);
    const int total4 = (n * D) / 4;
    gelu_stats_k<<<STATS_BLOCKS, 256, 0, stream>>>(x, bias, aggout, hbf, partials, total4);
    bn_reduce_params_k<<<128, 256, 0, stream>>>(partials, gamma, beta, ab, (float)n);
    bn_apply_k<<<(total4 + 255) / 256, 256, 0, stream>>>(hbf, out, ab, total4);
}

// Round 10
// 172.015 us; speedup vs baseline: 1.0566x; 1.0566x over previous
//
#include <hip/hip_runtime.h>
#include <math.h>

#define D 128
#define STATS_BLOCKS 512
#define SCAN_CHUNK 256

typedef __attribute__((ext_vector_type(8))) short short8;
typedef __attribute__((ext_vector_type(4))) float f32x4;

__device__ __forceinline__ unsigned short f2bf(float f) {
    unsigned u = __float_as_uint(f);
    unsigned r = (u + 0x7fff + ((u >> 16) & 1)) >> 16;   // RNE
    return (unsigned short)r;
}
__device__ __forceinline__ float bflo(unsigned u) { return __uint_as_float(u << 16); }
__device__ __forceinline__ float bfhi(unsigned u) { return __uint_as_float(u & 0xffff0000u); }

// ---------------- zero deg + deghist (replaces slow runtime fill) ----------------
__global__ __launch_bounds__(256) void zero_k(int* __restrict__ deg,
    int* __restrict__ deghist, int n)
{
    const int tid = blockIdx.x * 256 + threadIdx.x;
    const int stride = gridDim.x * 256;
    for (int i = tid; i < n; i += stride) deg[i] = 0;
    if (tid < 256) deghist[tid] = 0;
}

// ---------------- pack Wl|Wr into fragment-major bf16 ----------------
__global__ __launch_bounds__(256) void pack_w_k(const float* __restrict__ Wl,
    const float* __restrict__ Wr, unsigned short* __restrict__ wpack)
{
    const int lane = threadIdx.x & 63;
    const int wv = threadIdx.x >> 6;
    const int slot = blockIdx.x * 4 + wv;     // grid 16 -> slots 0..63
    const int ct = slot >> 2;
    const int kt = slot & 3;
    const float* W = (ct < 8) ? Wl : Wr;
    const int cb = (ct & 7) * 16 + (lane & 15);
    const int kb = kt * 32 + (lane >> 4) * 8;
    unsigned short v[8];
#pragma unroll
    for (int i = 0; i < 8; i++) v[i] = f2bf(W[(size_t)(kb + i) * D + cb]);
    *(uint4*)(wpack + ((size_t)slot << 9) + lane * 8) = *(uint4*)v;
}

// ---------------- MFMA GEMM: xl(bf16 packed) = x@Wl+bl, xr(f32) = x@Wr+br ----------------
__global__ __launch_bounds__(256) void gemm_mfma_k(const float* __restrict__ x,
    const unsigned short* __restrict__ wpack, const float* __restrict__ bl,
    const float* __restrict__ br, unsigned* __restrict__ xlb,
    float* __restrict__ xr, int n)
{
    const int lane = threadIdx.x & 63;
    const int wv = threadIdx.x >> 6;
    const int rt = blockIdx.x * 4 + wv;          // 16-row tile index
    if (rt * 16 >= n) return;
    const int r0 = rt * 16;
    const int ra = r0 + (lane & 15);
    const int r = ra < n ? ra : n - 1;
    const int ko = (lane >> 4) * 8;

    short8 a[4];
#pragma unroll
    for (int kt = 0; kt < 4; kt++) {
        const float* px = x + (size_t)r * D + kt * 32 + ko;
        float4 lo = *(const float4*)px;
        float4 hi = *(const float4*)(px + 4);
        short8 t;
        t[0] = (short)f2bf(lo.x); t[1] = (short)f2bf(lo.y);
        t[2] = (short)f2bf(lo.z); t[3] = (short)f2bf(lo.w);
        t[4] = (short)f2bf(hi.x); t[5] = (short)f2bf(hi.y);
        t[6] = (short)f2bf(hi.z); t[7] = (short)f2bf(hi.w);
        a[kt] = t;
    }

    f32x4 acc[16];
#pragma unroll
    for (int i = 0; i < 16; i++) acc[i] = (f32x4){0.f, 0.f, 0.f, 0.f};

#pragma unroll
    for (int kt = 0; kt < 4; kt++) {
#pragma unroll
        for (int ct = 0; ct < 16; ct++) {
            short8 b = *(const short8*)(wpack + (((size_t)(ct * 4 + kt)) << 9) + lane * 8);
            acc[ct] = __builtin_amdgcn_mfma_f32_16x16x32_bf16(a[kt], b, acc[ct], 0, 0, 0);
        }
    }

    const int colb = lane & 15;
    const int rbase = r0 + (lane >> 4) * 4;
#pragma unroll
    for (int ct = 8; ct < 16; ct++) {
        const int c = (ct - 8) * 16 + colb;
        const float bb = br[c];
#pragma unroll
        for (int reg = 0; reg < 4; reg++) {
            const int row = rbase + reg;
            if (row < n) xr[(size_t)row * D + c] = acc[ct][reg] + bb;
        }
    }
#pragma unroll
    for (int ct = 0; ct < 8; ct++) {
        const int c = ct * 16 + colb;
        const float bb = bl[c];
#pragma unroll
        for (int reg = 0; reg < 4; reg++) {
            unsigned mybf = f2bf(acc[ct][reg] + bb);
            unsigned other = (unsigned)__shfl_xor((int)mybf, 1);
            if ((lane & 1) == 0) {
                const int row = rbase + reg;
                if (row < n) xlb[(size_t)row * 64 + (c >> 1)] = mybf | (other << 16);
            }
        }
    }
}

// ---------------- CSR build: histogram ----------------
__global__ __launch_bounds__(256) void hist_k(const int* __restrict__ ei,
    int* __restrict__ deg, int E)
{
    int e = blockIdx.x * blockDim.x + threadIdx.x;
    if (e < E) atomicAdd(&deg[ei[E + e]], 1);
}

// ---------------- scan stage 1: per-block chunk sums + degree histogram ----------------
__global__ __launch_bounds__(256) void scan_sum_k(const int* __restrict__ deg,
    int* __restrict__ bsum, int* __restrict__ deghist, int n)
{
    __shared__ int lh[256];
    const int t = threadIdx.x;
    lh[t] = 0;
    __syncthreads();
    const int i = blockIdx.x * SCAN_CHUNK + t;
    int s = 0;
    if (i < n) {
        s = deg[i];
        atomicAdd(&lh[min(s, 255)], 1);
    }
#pragma unroll
    for (int off = 32; off > 0; off >>= 1) s += __shfl_xor(s, off);
    __shared__ int ws_[4];
    const int lane = t & 63, w = t >> 6;
    if (lane == 0) ws_[w] = s;
    __syncthreads();
    if (t == 0) bsum[blockIdx.x] = ws_[0] + ws_[1] + ws_[2] + ws_[3];
    if (lh[t]) atomicAdd(&deghist[t], lh[t]);
}

// ---------------- scan stage 2: exclusive scan of block sums + degree-bin offsets ----------------
__global__ __launch_bounds__(256) void scan_off_k(const int* __restrict__ bsum,
    int* __restrict__ boff, int* __restrict__ rowptr,
    const int* __restrict__ deghist, int* __restrict__ degcur, int nb, int n)
{
    const int t = threadIdx.x;
    const int lane = t & 63, w = t >> 6;
    // --- scan of block sums ---
    int v = (t < nb) ? bsum[t] : 0;
    int inc = v;
#pragma unroll
    for (int off = 1; off < 64; off <<= 1) {
        int u = __shfl_up(inc, off);
        if (lane >= off) inc += u;
    }
    __shared__ int wsum[4], wpre[4];
    if (lane == 63) wsum[w] = inc;
    __syncthreads();
    if (t == 0) {
        int r = 0;
#pragma unroll
        for (int j = 0; j < 4; j++) { wpre[j] = r; r += wsum[j]; }
        rowptr[n] = r;
    }
    __syncthreads();
    if (t < nb) boff[t] = inc - v + wpre[w];
    // --- exclusive scan of degree histogram ---
    int dv = deghist[t];
    int dinc = dv;
#pragma unroll
    for (int off = 1; off < 64; off <<= 1) {
        int u = __shfl_up(dinc, off);
        if (lane >= off) dinc += u;
    }
    __shared__ int w2sum[4], w2pre[4];
    if (lane == 63) w2sum[w] = dinc;
    __syncthreads();
    if (t == 0) {
        int r = 0;
#pragma unroll
        for (int j = 0; j < 4; j++) { w2pre[j] = r; r += w2sum[j]; }
    }
    __syncthreads();
    degcur[t] = dinc - dv + w2pre[w];
}

// ---------------- scan stage 3: in-block scan + offset + degree-sorted node order ----------------
__global__ __launch_bounds__(256) void scan_fin_k(int* __restrict__ deg,
    const int* __restrict__ boff, int* __restrict__ rowptr,
    int* __restrict__ degcur, int* __restrict__ nodeord, int n)
{
    __shared__ int wsum[4], wpre[4];
    __shared__ int lh[256], lbase[256];
    const int t = threadIdx.x;
    const int i = blockIdx.x * SCAN_CHUNK + t;
    lh[t] = 0;
    int v = (i < n) ? deg[i] : 0;
    const int bin = min(v, 255);
    const int lane = t & 63, w = t >> 6;
    int inc = v;
#pragma unroll
    for (int off = 1; off < 64; off <<= 1) {
        int u = __shfl_up(inc, off);
        if (lane >= off) inc += u;
    }
    if (lane == 63) wsum[w] = inc;
    __syncthreads();
    if (t == 0) {
        int r = 0;
#pragma unroll
        for (int j = 0; j < 4; j++) { wpre[j] = r; r += wsum[j]; }
    }
    __syncthreads();
    int rank = 0;
    if (i < n) {
        rank = atomicAdd(&lh[bin], 1);
        int ex = inc - v + wpre[w] + boff[blockIdx.x];
        rowptr[i] = ex;
        deg[i] = ex;                 // scatter cursor
    }
    __syncthreads();
    lbase[t] = lh[t] ? atomicAdd(&degcur[t], lh[t]) : 0;
    __syncthreads();
    if (i < n) nodeord[lbase[bin] + rank] = i;
}

// ---------------- CSR build: scatter {src, ea} pairs into dst-grouped order ----------------
__global__ __launch_bounds__(256) void scatter_k(const int* __restrict__ ei,
    const float* __restrict__ ea, int* __restrict__ cursor,
    uint2* __restrict__ edges, int E)
{
    int e = blockIdx.x * blockDim.x + threadIdx.x;
    if (e >= E) return;
    int dst = ei[E + e];
    int pos = atomicAdd(&cursor[dst], 1);
    edges[pos] = make_uint2((unsigned)ei[e], __float_as_uint(ea[e]));
}

// ---------------- fused edge logits + online softmax + aggregate ----------------
// one 16-lane group per dst node (4 independent nodes/wave); nodes walked in
// DESCENDING degree order (heavy blocks dispatch first -> no straggler tail,
// and the wave's 4 nodes still have near-equal degree). Lane owns 8 features.
// Output packed bf16 into aggout (d_out's first half).
__global__ __launch_bounds__(256) void agg_k(const unsigned* __restrict__ xlb,
    const float* __restrict__ xr, const int* __restrict__ rowptr,
    const uint2* __restrict__ edges, const float* __restrict__ We,
    const float* __restrict__ att, const int* __restrict__ nodeord,
    unsigned* __restrict__ aggout, int n)
{
    const int gg = (blockIdx.x * 256 + threadIdx.x) >> 4;
    const int li = threadIdx.x & 15;
    if (gg >= n) return;
    const int v = nodeord[n - 1 - gg];   // descending degree
    const int beg = rowptr[v];
    const int end = rowptr[v + 1];
    const int f0 = li * 8;

    float xrv[8], wev[8], atv[8];
    {
        float4 a0 = *(const float4*)(xr + (size_t)v * D + f0);
        float4 a1 = *(const float4*)(xr + (size_t)v * D + f0 + 4);
        xrv[0]=a0.x; xrv[1]=a0.y; xrv[2]=a0.z; xrv[3]=a0.w;
        xrv[4]=a1.x; xrv[5]=a1.y; xrv[6]=a1.z; xrv[7]=a1.w;
        float4 w0 = *(const float4*)(We + f0);
        float4 w1 = *(const float4*)(We + f0 + 4);
        wev[0]=w0.x; wev[1]=w0.y; wev[2]=w0.z; wev[3]=w0.w;
        wev[4]=w1.x; wev[5]=w1.y; wev[6]=w1.z; wev[7]=w1.w;
        float4 t0 = *(const float4*)(att + f0);
        float4 t1 = *(const float4*)(att + f0 + 4);
        atv[0]=t0.x; atv[1]=t0.y; atv[2]=t0.z; atv[3]=t0.w;
        atv[4]=t1.x; atv[5]=t1.y; atv[6]=t1.z; atv[7]=t1.w;
    }

    float m = -1e30f, s = 0.f;
    float acc[8];
#pragma unroll
    for (int k = 0; k < 8; k++) acc[k] = 0.f;

    int j = beg;
    uint2 e2 = make_uint2(0u, 0u);
    uint4 xb4 = make_uint4(0u, 0u, 0u, 0u);
    if (j < end) {
        e2 = edges[j];
        xb4 = *(const uint4*)(xlb + (size_t)e2.x * 64 + li * 4);
    }
    while (j < end) {
        const int jn = j + 1;
        const int jc = jn < end ? jn : end - 1;     // clamped prefetch
        const uint2 e2n = edges[jc];
        const uint4 xbn = *(const uint4*)(xlb + (size_t)e2n.x * 64 + li * 4);

        const float eav = __uint_as_float(e2.y);
        float xv[8];
        xv[0] = bflo(xb4.x); xv[1] = bfhi(xb4.x);
        xv[2] = bflo(xb4.y); xv[3] = bfhi(xb4.y);
        xv[4] = bflo(xb4.z); xv[5] = bfhi(xb4.z);
        xv[6] = bflo(xb4.w); xv[7] = bfhi(xb4.w);

        float p = 0.f;
#pragma unroll
        for (int k = 0; k < 8; k++) {
            float t = fmaf(eav, wev[k], xrv[k]) + xv[k];
            t = fmaxf(t, 0.2f * t);                 // leaky relu
            p = fmaf(t, atv[k], p);
        }
#pragma unroll
        for (int off = 8; off >= 1; off >>= 1) p += __shfl_xor(p, off);

        const float pm = fmaxf(m, p);
        const float sc = __expf(m - pm);
        const float w  = __expf(p - pm);
        s = s * sc + w;
#pragma unroll
        for (int k = 0; k < 8; k++) acc[k] = fmaf(acc[k], sc, w * xv[k]);
        m = pm;

        e2 = e2n; xb4 = xbn; j = jn;
    }

    const float inv = 1.f / (s + 1e-16f);           // deg==0 -> acc=0 -> out=0
    unsigned o0 = (unsigned)f2bf(acc[0]*inv) | ((unsigned)f2bf(acc[1]*inv) << 16);
    unsigned o1 = (unsigned)f2bf(acc[2]*inv) | ((unsigned)f2bf(acc[3]*inv) << 16);
    unsigned o2 = (unsigned)f2bf(acc[4]*inv) | ((unsigned)f2bf(acc[5]*inv) << 16);
    unsigned o3 = (unsigned)f2bf(acc[6]*inv) | ((unsigned)f2bf(acc[7]*inv) << 16);
    *(uint4*)(aggout + (size_t)v * 64 + li * 4) = make_uint4(o0, o1, o2, o3);
}

// ---------------- residual + GELU(erf) + BN stats (bf16 in/out, atomic-free) ----------------
__global__ __launch_bounds__(256) void gelu_stats_k(const float* __restrict__ x,
    const float* __restrict__ bias, const unsigned* __restrict__ aggout,
    unsigned* __restrict__ hbf, float* __restrict__ partials, int total4)
{
    const int t = threadIdx.x;
    const int c0 = (t & 31) * 4;
    const float4 bv = *(const float4*)&bias[c0];
    float sum[4] = {0.f, 0.f, 0.f, 0.f}, sq[4] = {0.f, 0.f, 0.f, 0.f};
    const int stride = gridDim.x * blockDim.x;
    for (int i4 = blockIdx.x * blockDim.x + t; i4 < total4; i4 += stride) {
        float4 xv = ((const float4*)x)[i4];
        uint2 ag = *(const uint2*)(aggout + (size_t)i4 * 2);
        float hv[4] = {xv.x + bflo(ag.x) + bv.x, xv.y + bfhi(ag.x) + bv.y,
                       xv.z + bflo(ag.y) + bv.z, xv.w + bfhi(ag.y) + bv.w};
        float res[4];
#pragma unroll
        for (int j = 0; j < 4; j++) {
            float ge = 0.5f * hv[j] * (1.f + erff(hv[j] * 0.70710678118654752f));
            res[j] = ge;
            sum[j] += ge;
            sq[j] += ge * ge;
        }
        uint2 hp;
        hp.x = (unsigned)f2bf(res[0]) | ((unsigned)f2bf(res[1]) << 16);
        hp.y = (unsigned)f2bf(res[2]) | ((unsigned)f2bf(res[3]) << 16);
        *(uint2*)(hbf + (size_t)i4 * 2) = hp;
    }
    __shared__ float red[8][128];
    const int slot = t >> 5;
#pragma unroll
    for (int j = 0; j < 4; j++) red[slot][c0 + j] = sum[j];
    __syncthreads();
    if (t < 128) {
        float tot = 0.f;
#pragma unroll
        for (int s2 = 0; s2 < 8; s2++) tot += red[s2][t];
        partials[(size_t)t * STATS_BLOCKS + blockIdx.x] = tot;
    }
    __syncthreads();
#pragma unroll
    for (int j = 0; j < 4; j++) red[slot][c0 + j] = sq[j];
    __syncthreads();
    if (t < 128) {
        float tot = 0.f;
#pragma unroll
        for (int s2 = 0; s2 < 8; s2++) tot += red[s2][t];
        partials[(size_t)(128 + t) * STATS_BLOCKS + blockIdx.x] = tot;
    }
}

// ---------------- reduce partials + fold BN params ----------------
__global__ __launch_bounds__(256) void bn_reduce_params_k(const float* __restrict__ partials,
    const float* __restrict__ gamma, const float* __restrict__ beta,
    float* __restrict__ ab, float n)
{
    const int c = blockIdx.x;      // 0..127
    const int t = threadIdx.x;     // 256
    float s = 0.f, q = 0.f;
    for (int b = t; b < STATS_BLOCKS; b += 256) {
        s += partials[(size_t)c * STATS_BLOCKS + b];
        q += partials[(size_t)(128 + c) * STATS_BLOCKS + b];
    }
#pragma unroll
    for (int off = 32; off > 0; off >>= 1) {
        s += __shfl_xor(s, off);
        q += __shfl_xor(q, off);
    }
    __shared__ float ss[4], qq[4];
    const int lane = t & 63, w = t >> 6;
    if (lane == 0) { ss[w] = s; qq[w] = q; }
    __syncthreads();
    if (t == 0) {
        float S = ss[0] + ss[1] + ss[2] + ss[3];
        float Q = qq[0] + qq[1] + qq[2] + qq[3];
        float mean = S / n;
        float var = Q / n - mean * mean;
        float a = rsqrtf(var + 1e-5f) * gamma[c];
        ab[c] = a;
        ab[c + 128] = beta[c] - mean * a;
    }
}

// ---------------- BN apply (bf16 h -> f32 out) ----------------
__global__ __launch_bounds__(256) void bn_apply_k(const unsigned* __restrict__ hbf,
    float* __restrict__ out, const float* __restrict__ ab, int total4)
{
    int i4 = blockIdx.x * blockDim.x + threadIdx.x;
    if (i4 >= total4) return;
    int cg = i4 & 31;
    uint2 hp = *(const uint2*)(hbf + (size_t)i4 * 2);
    float4 a = ((const float4*)ab)[cg];
    float4 b = ((const float4*)(ab + 128))[cg];
    ((float4*)out)[i4] = make_float4(bflo(hp.x) * a.x + b.x, bfhi(hp.x) * a.y + b.y,
                                     bflo(hp.y) * a.z + b.z, bfhi(hp.y) * a.w + b.w);
}

extern "C" void kernel_launch(void* const* d_in, const int* in_sizes, int n_in,
                              void* d_out, int out_size, void* d_ws, size_t ws_size,
                              hipStream_t stream)
{
    const float* x    = (const float*)d_in[0];
    const int*   ei   = (const int*)d_in[1];
    const float* ea   = (const float*)d_in[2];
    const float* Wl   = (const float*)d_in[3];
    const float* bl   = (const float*)d_in[4];
    const float* Wr   = (const float*)d_in[5];
    const float* br   = (const float*)d_in[6];
    const float* We   = (const float*)d_in[7];
    const float* att  = (const float*)d_in[8];
    const float* bias = (const float*)d_in[9];
    const float* gamma= (const float*)d_in[10];
    const float* beta = (const float*)d_in[11];
    float* out = (float*)d_out;

    const int n = in_sizes[0] / D;
    const int E = in_sizes[1] / 2;
    const int nb = (n + SCAN_CHUNK - 1) / SCAN_CHUNK;

    char* ws = (char*)d_ws;
    unsigned short* wpack = (unsigned short*)ws;        // 32768 bf16 (64 KB)
    unsigned* xlb = (unsigned*)(ws + 65536);            // n*64 uints (bf16 xl); reused as hbf
    float* xr = (float*)(xlb + (size_t)n * 64);         // n*D floats
    int* deg = (int*)(xr + (size_t)n * D);              // n (becomes cursor)
    int* rowptr = deg + n;                              // n+1
    int* deghist = rowptr + n + 1;                      // 256
    int* degcur = deghist + 256;                        // 256
    int* nodeord = degcur + 256;                        // n
    int* bsum = nodeord + n;                            // nb
    int* boff = bsum + nb;                              // nb
    uintptr_t ep = ((uintptr_t)(boff + nb) + 7) & ~(uintptr_t)7;
    uint2* edges = (uint2*)ep;                          // E uint2
    float* partials = (float*)(edges + E);              // 256*STATS_BLOCKS
    float* ab = partials + 256 * STATS_BLOCKS;          // 256

    unsigned* aggout = (unsigned*)d_out;                // n*64 uints (bf16), first half of out
    unsigned* hbf = xlb;                                // reuse after agg_k

    zero_k<<<98, 256, 0, stream>>>(deg, deghist, n);
    pack_w_k<<<16, 256, 0, stream>>>(Wl, Wr, wpack);
    const int nrt = (n + 15) / 16;
    gemm_mfma_k<<<(nrt + 3) / 4, 256, 0, stream>>>(x, wpack, bl, br, xlb, xr, n);
    hist_k<<<(E + 255) / 256, 256, 0, stream>>>(ei, deg, E);
    scan_sum_k<<<nb, 256, 0, stream>>>(deg, bsum, deghist, n);
    scan_off_k<<<1, 256, 0, stream>>>(bsum, boff, rowptr, deghist, degcur, nb, n);
    scan_fin_k<<<nb, 256, 0, stream>>>(deg, boff, rowptr, degcur, nodeord, n);
    scatter_k<<<(E + 255) / 256, 256, 0, stream>>>(ei, ea, deg, edges, E);
    agg_k<<<(n + 15) / 16, 256, 0, stream>>>(xlb, xr, rowptr, edges, We, att, nodeord, aggout, n);
    const int total4 = (n * D) / 4;
    gelu_stats_k<<<STATS_BLOCKS, 256, 0, stream>>>(x, bias, aggout, hbf, partials, total4);
    bn_reduce_params_k<<<128, 256, 0, stream>>>(partials, gamma, beta, ab, (float)n);
    bn_apply_k<<<(total4 + 255) / 256, 256, 0, stream>>>(hbf, out, ab, total4);
}